// Round 1
// baseline (1015.227 us; speedup 1.0000x reference)
//
#include <hip/hip_runtime.h>
#include <cstdint>
#include <cstddef>

#define BB 64
#define DD 1024
#define HH 8
#define VV 32000
#define H4 4096
#define DSPLIT 8

// ws layout (floats)
#define OFF_HT     0            // 1024*64
#define OFF_W1T    65536        // 1024*4096
#define OFF_RPART  4259840      // DSPLIT*64*4096
#define OFF_R      6356992      // 64*4096
#define OFF_NLL    6619136      // 512
#define OFF_CNT    6619648      // 512
#define OFF_SCAL   6620160      // 4

// d_out layout (floats)
#define OFF_LOGITS 0
#define OFF_GATE   16384000
#define OFF_ACT    16384512
#define OFF_LOSS   16385024

// ---------------- generic 32x32 tiled transpose: in[R][C] -> out[C][R] -------
__global__ void k_transpose(const float* __restrict__ in, float* __restrict__ out,
                            int R, int C) {
    __shared__ float t[32][33];
    int r0 = blockIdx.y * 32, c0 = blockIdx.x * 32;
    int tx = threadIdx.x & 31, ty = threadIdx.x >> 5;   // 256 threads: ty 0..7
    for (int i = 0; i < 32; i += 8) {
        int r = r0 + ty + i, c = c0 + tx;
        if (r < R && c < C) t[ty + i][tx] = in[(size_t)r * C + c];
    }
    __syncthreads();
    for (int i = 0; i < 32; i += 8) {
        int r = c0 + ty + i, c = r0 + tx;
        if (r < C && c < R) out[(size_t)r * R + c] = t[tx][ty + i];
    }
}

// ---------------- router layer 1 partial: rpart[ds][b][j] ---------------------
__global__ __launch_bounds__(256) void k_router1_partial(
    const float* __restrict__ hT, const float* __restrict__ w1T,
    float* __restrict__ rpart) {
    __shared__ float hs[128 * 64];
    int j  = blockIdx.x * 256 + threadIdx.x;
    int d0 = blockIdx.y * 128;
    for (int i = threadIdx.x; i < 128 * 64; i += 256) hs[i] = hT[d0 * 64 + i];
    __syncthreads();
    float acc[BB];
#pragma unroll
    for (int b = 0; b < BB; ++b) acc[b] = 0.f;
    const float* wp = w1T + (size_t)d0 * H4 + j;
#pragma unroll 4
    for (int d = 0; d < 128; ++d) {
        float w = wp[(size_t)d * H4];
        const float* hr = hs + d * 64;
#pragma unroll
        for (int b4 = 0; b4 < 16; ++b4) {
            float4 h4 = *(const float4*)(hr + b4 * 4);
            acc[b4 * 4 + 0] = fmaf(h4.x, w, acc[b4 * 4 + 0]);
            acc[b4 * 4 + 1] = fmaf(h4.y, w, acc[b4 * 4 + 1]);
            acc[b4 * 4 + 2] = fmaf(h4.z, w, acc[b4 * 4 + 2]);
            acc[b4 * 4 + 3] = fmaf(h4.w, w, acc[b4 * 4 + 3]);
        }
    }
    float* rp = rpart + (size_t)blockIdx.y * (BB * H4) + j;
#pragma unroll
    for (int b = 0; b < BB; ++b) rp[(size_t)b * H4] = acc[b];
}

// ---------------- reduce partials + bias + exact GELU -> r[b][j] -------------
__global__ void k_router1_reduce(const float* __restrict__ rpart,
                                 const float* __restrict__ b1,
                                 float* __restrict__ r) {
    int idx = blockIdx.x * 256 + threadIdx.x;   // b*4096 + j
    int j = idx & (H4 - 1);
    float s = 0.f;
#pragma unroll
    for (int p = 0; p < DSPLIT; ++p) s += rpart[(size_t)p * (BB * H4) + idx];
    s += b1[j];
    r[idx] = 0.5f * s * (1.0f + erff(s * 0.70710678118654752f));
}

// ---------------- router layer 2: gate[b][h] ---------------------------------
__global__ void k_router2(const float* __restrict__ r, const float* __restrict__ w2,
                          const float* __restrict__ b2, float* __restrict__ gate) {
    int b = blockIdx.x;
    int h = threadIdx.x >> 5;
    int lane = threadIdx.x & 31;
    const float* rr = r + (size_t)b * H4;
    const float* ww = w2 + (size_t)h * H4;
    float s = 0.f;
    for (int j = lane; j < H4; j += 32) s = fmaf(rr[j], ww[j], s);
    for (int off = 16; off > 0; off >>= 1) s += __shfl_down(s, off, 32);
    if (lane == 0) gate[b * HH + h] = s + b2[h];
}

// ---------------- top-k routing + BCE/LB/entropy/budget ----------------------
__global__ void k_routing_aux(const float* __restrict__ gate, const int* __restrict__ kmaxp,
                              float* __restrict__ act_out, float* __restrict__ scal) {
    __shared__ float af[64][8];
    __shared__ float bces[64], ents[64];
    int b = threadIdx.x;   // 64 threads
    float g[8];
#pragma unroll
    for (int h = 0; h < 8; ++h) g[h] = gate[b * 8 + h];
    int k = kmaxp[0]; k = k < 0 ? 0 : (k > 8 ? 8 : k);
    bool act[8] = {false, false, false, false, false, false, false, false};
    for (int s = 0; s < k; ++s) {
        int best = -1; float bv = -1e30f;
#pragma unroll
        for (int h = 0; h < 8; ++h)
            if (!act[h] && g[h] > bv) { bv = g[h]; best = h; }
        act[best] = true;
    }
    float m = -1e30f;
#pragma unroll
    for (int h = 0; h < 8; ++h) m = fmaxf(m, g[h]);
    float se = 0.f, ex[8];
#pragma unroll
    for (int h = 0; h < 8; ++h) { ex[h] = expf(g[h] - m); se += ex[h]; }
    float bce = 0.f, ent = 0.f;
#pragma unroll
    for (int h = 0; h < 8; ++h) {
        float t = act[h] ? 1.f : 0.f;
        bce += fmaxf(g[h], 0.f) - g[h] * t + log1pf(expf(-fabsf(g[h])));
        float p = ex[h] / se;
        ent -= p * logf(p + 1e-9f);
        af[b][h] = t;
        act_out[b * 8 + h] = t;
    }
    bces[b] = bce; ents[b] = ent;
    __syncthreads();
    if (b == 0) {
        float bsum = 0.f, esum = 0.f, asum = 0.f, lb = 0.f;
        for (int i = 0; i < 64; ++i) { bsum += bces[i]; esum += ents[i]; }
        for (int h = 0; h < 8; ++h) {
            float f = 0.f;
            for (int i = 0; i < 64; ++i) f += af[i][h];
            asum += f;
            float fr = f / 64.f - 0.125f;
            lb += fr * fr;
        }
        scal[0] = bsum / 512.f;   // bce mean
        scal[1] = lb;             // load balance
        scal[2] = esum / 64.f;    // entropy mean
        scal[3] = asum / 512.f;   // budget
    }
}

// ---------------- big GEMM: logits[b][h][v] ----------------------------------
__global__ __launch_bounds__(256, 2) void k_heads_gemm(
    const float* __restrict__ hT, const float* __restrict__ W,
    float* __restrict__ out) {
    __shared__ float hs[128 * 64];
    const int h = blockIdx.y;
    int v = blockIdx.x * 512 + threadIdx.x * 2;
    const bool ok = v <= (VV - 2);
    if (!ok) v = VV - 2;
    float2 acc[BB];
#pragma unroll
    for (int b = 0; b < BB; ++b) { acc[b].x = 0.f; acc[b].y = 0.f; }
    const float* wp = W + (size_t)h * DD * VV + v;
    for (int dc = 0; dc < DD; dc += 128) {
        __syncthreads();
        for (int i = threadIdx.x; i < 128 * 64; i += 256) hs[i] = hT[dc * 64 + i];
        __syncthreads();
        const float* wpd = wp + (size_t)dc * VV;
#pragma unroll 4
        for (int d = 0; d < 128; ++d) {
            float2 wv = *(const float2*)(wpd);
            wpd += VV;
            const float* hr = hs + d * 64;
#pragma unroll
            for (int b4 = 0; b4 < 16; ++b4) {
                float4 h4 = *(const float4*)(hr + b4 * 4);
                acc[b4 * 4 + 0].x = fmaf(h4.x, wv.x, acc[b4 * 4 + 0].x);
                acc[b4 * 4 + 0].y = fmaf(h4.x, wv.y, acc[b4 * 4 + 0].y);
                acc[b4 * 4 + 1].x = fmaf(h4.y, wv.x, acc[b4 * 4 + 1].x);
                acc[b4 * 4 + 1].y = fmaf(h4.y, wv.y, acc[b4 * 4 + 1].y);
                acc[b4 * 4 + 2].x = fmaf(h4.z, wv.x, acc[b4 * 4 + 2].x);
                acc[b4 * 4 + 2].y = fmaf(h4.z, wv.y, acc[b4 * 4 + 2].y);
                acc[b4 * 4 + 3].x = fmaf(h4.w, wv.x, acc[b4 * 4 + 3].x);
                acc[b4 * 4 + 3].y = fmaf(h4.w, wv.y, acc[b4 * 4 + 3].y);
            }
        }
    }
    if (ok) {
#pragma unroll
        for (int b = 0; b < BB; ++b)
            *(float2*)(out + ((size_t)(b * HH + h)) * VV + v) = acc[b];
    }
}

// ---------------- masked CE per (b,h): two-pass log-softmax ------------------
__global__ __launch_bounds__(256) void k_ce(
    const float* __restrict__ logits, const float* __restrict__ act,
    const int* __restrict__ labels, float* __restrict__ nllv, float* __restrict__ cnt) {
    int p = blockIdx.x;   // b*8 + h
    const float* lp = logits + (size_t)p * VV;
    __shared__ float red[256];
    float m = -1e30f;
    for (int i = threadIdx.x; i < VV; i += 256) m = fmaxf(m, lp[i]);
    red[threadIdx.x] = m; __syncthreads();
    for (int s = 128; s > 0; s >>= 1) {
        if (threadIdx.x < s) red[threadIdx.x] = fmaxf(red[threadIdx.x], red[threadIdx.x + s]);
        __syncthreads();
    }
    m = red[0]; __syncthreads();
    float se = 0.f;
    for (int i = threadIdx.x; i < VV; i += 256) se += expf(lp[i] - m);
    red[threadIdx.x] = se; __syncthreads();
    for (int s = 128; s > 0; s >>= 1) {
        if (threadIdx.x < s) red[threadIdx.x] += red[threadIdx.x + s];
        __syncthreads();
    }
    if (threadIdx.x == 0) {
        int lab = labels[p];
        float nll = -(lp[lab] - m - logf(red[0]));
        bool valid = (act[p] > 0.5f) && (lab != 0);
        nllv[p] = valid ? nll : 0.f;
        cnt[p]  = valid ? 1.f : 0.f;
    }
}

// ---------------- final scalar loss ------------------------------------------
__global__ void k_final_loss(const float* __restrict__ nllv, const float* __restrict__ cnt,
                             const float* __restrict__ scal, float* __restrict__ lossp) {
    __shared__ float r1[256], r2[256];
    float a = nllv[threadIdx.x] + nllv[threadIdx.x + 256];
    float c = cnt[threadIdx.x]  + cnt[threadIdx.x + 256];
    r1[threadIdx.x] = a; r2[threadIdx.x] = c; __syncthreads();
    for (int s = 128; s > 0; s >>= 1) {
        if (threadIdx.x < s) { r1[threadIdx.x] += r1[threadIdx.x + s]; r2[threadIdx.x] += r2[threadIdx.x + s]; }
        __syncthreads();
    }
    if (threadIdx.x == 0) {
        float nv = r2[0] < 1.f ? 1.f : r2[0];
        float ce = r1[0] / nv;
        lossp[0] = ce + 1.0f * scal[0] + 0.2f * scal[1] + 0.01f * scal[2] + 0.05f * scal[3];
    }
}

extern "C" void kernel_launch(void* const* d_in, const int* in_sizes, int n_in,
                              void* d_out, int out_size, void* d_ws, size_t ws_size,
                              hipStream_t stream) {
    const float* hidden = (const float*)d_in[0];
    const float* w1     = (const float*)d_in[1];
    const float* b1     = (const float*)d_in[2];
    const float* w2     = (const float*)d_in[3];
    const float* b2     = (const float*)d_in[4];
    const float* W      = (const float*)d_in[5];
    const int*   labels = (const int*)d_in[6];
    const int*   kmaxp  = (const int*)d_in[7];

    float* ws  = (float*)d_ws;
    float* out = (float*)d_out;

    float* hT    = ws + OFF_HT;
    float* w1T   = ws + OFF_W1T;
    float* rpart = ws + OFF_RPART;
    float* r     = ws + OFF_R;
    float* nllv  = ws + OFF_NLL;
    float* cntv  = ws + OFF_CNT;
    float* scal  = ws + OFF_SCAL;

    float* logits = out + OFF_LOGITS;
    float* gate   = out + OFF_GATE;
    float* activ  = out + OFF_ACT;
    float* lossp  = out + OFF_LOSS;

    // 1. hidden [64][1024] -> hT [1024][64]
    k_transpose<<<dim3(32, 2), 256, 0, stream>>>(hidden, hT, BB, DD);
    // 2. w1 [4096][1024] -> w1T [1024][4096]
    k_transpose<<<dim3(32, 128), 256, 0, stream>>>(w1, w1T, H4, DD);
    // 3. router layer 1 partial GEMM
    k_router1_partial<<<dim3(16, DSPLIT), 256, 0, stream>>>(hT, w1T, rpart);
    // 4. reduce + bias + GELU
    k_router1_reduce<<<dim3(1024), 256, 0, stream>>>(rpart, b1, r);
    // 5. router layer 2
    k_router2<<<dim3(64), 256, 0, stream>>>(r, w2, b2, gate);
    // 6. routing / aux losses
    k_routing_aux<<<dim3(1), 64, 0, stream>>>(gate, kmaxp, activ, scal);
    // 7. big GEMM
    k_heads_gemm<<<dim3(63, 8), 256, 0, stream>>>(hT, W, logits);
    // 8. masked CE
    k_ce<<<dim3(512), 256, 0, stream>>>(logits, activ, labels, nllv, cntv);
    // 9. final loss
    k_final_loss<<<dim3(1), 256, 0, stream>>>(nllv, cntv, scal, lossp);
}

// Round 3
// 437.230 us; speedup vs baseline: 2.3220x; 2.3220x over previous
//
#include <hip/hip_runtime.h>
#include <cstdint>
#include <cstddef>

#define BB 64
#define DD 1024
#define HH 8
#define VV 32000
#define H4 4096
#define DSPLIT 8

// ws layout (floats)
#define OFF_HT     0            // 1024*64
#define OFF_W1T    65536        // 1024*4096
#define OFF_RPART  4259840      // DSPLIT*64*4096 (hA f16 reuses this after reduce)
#define OFF_R      6356992      // 64*4096
#define OFF_NLL    6619136      // 512
#define OFF_CNT    6619648      // 512
#define OFF_SCAL   6620160      // 4

// d_out layout (floats)
#define OFF_LOGITS 0
#define OFF_GATE   16384000
#define OFF_ACT    16384512
#define OFF_LOSS   16385024

typedef __attribute__((ext_vector_type(8))) _Float16 f16x8;
typedef __attribute__((ext_vector_type(4))) float f32x4;

// ---------------- generic 32x32 tiled transpose: in[R][C] -> out[C][R] -------
__global__ void k_transpose(const float* __restrict__ in, float* __restrict__ out,
                            int R, int C) {
    __shared__ float t[32][33];
    int r0 = blockIdx.y * 32, c0 = blockIdx.x * 32;
    int tx = threadIdx.x & 31, ty = threadIdx.x >> 5;   // 256 threads: ty 0..7
    for (int i = 0; i < 32; i += 8) {
        int r = r0 + ty + i, c = c0 + tx;
        if (r < R && c < C) t[ty + i][tx] = in[(size_t)r * C + c];
    }
    __syncthreads();
    for (int i = 0; i < 32; i += 8) {
        int r = c0 + ty + i, c = r0 + tx;
        if (r < C && c < R) out[(size_t)r * R + c] = t[tx][ty + i];
    }
}

// ---------------- router layer 1 partial: rpart[ds][b][j] ---------------------
__global__ __launch_bounds__(256) void k_router1_partial(
    const float* __restrict__ hT, const float* __restrict__ w1T,
    float* __restrict__ rpart) {
    __shared__ float hs[128 * 64];
    int j  = blockIdx.x * 256 + threadIdx.x;
    int d0 = blockIdx.y * 128;
    for (int i = threadIdx.x; i < 128 * 64; i += 256) hs[i] = hT[d0 * 64 + i];
    __syncthreads();
    float acc[BB];
#pragma unroll
    for (int b = 0; b < BB; ++b) acc[b] = 0.f;
    const float* wp = w1T + (size_t)d0 * H4 + j;
#pragma unroll 4
    for (int d = 0; d < 128; ++d) {
        float w = wp[(size_t)d * H4];
        const float* hr = hs + d * 64;
#pragma unroll
        for (int b4 = 0; b4 < 16; ++b4) {
            float4 h4 = *(const float4*)(hr + b4 * 4);
            acc[b4 * 4 + 0] = fmaf(h4.x, w, acc[b4 * 4 + 0]);
            acc[b4 * 4 + 1] = fmaf(h4.y, w, acc[b4 * 4 + 1]);
            acc[b4 * 4 + 2] = fmaf(h4.z, w, acc[b4 * 4 + 2]);
            acc[b4 * 4 + 3] = fmaf(h4.w, w, acc[b4 * 4 + 3]);
        }
    }
    float* rp = rpart + (size_t)blockIdx.y * (BB * H4) + j;
#pragma unroll
    for (int b = 0; b < BB; ++b) rp[(size_t)b * H4] = acc[b];
}

// ---------------- reduce partials + bias + exact GELU -> r[b][j] -------------
__global__ void k_router1_reduce(const float* __restrict__ rpart,
                                 const float* __restrict__ b1,
                                 float* __restrict__ r) {
    int idx = blockIdx.x * 256 + threadIdx.x;   // b*4096 + j
    int j = idx & (H4 - 1);
    float s = 0.f;
#pragma unroll
    for (int p = 0; p < DSPLIT; ++p) s += rpart[(size_t)p * (BB * H4) + idx];
    s += b1[j];
    r[idx] = 0.5f * s * (1.0f + erff(s * 0.70710678118654752f));
}

// ---------------- hidden fp32 -> f16 -----------------------------------------
__global__ void k_h2f16(const float* __restrict__ in, _Float16* __restrict__ out) {
    int i = blockIdx.x * 256 + threadIdx.x;   // 64*1024 = 65536 elems
    out[i] = (_Float16)in[i];
}

// ---------------- router layer 2: gate[b][h] ---------------------------------
__global__ void k_router2(const float* __restrict__ r, const float* __restrict__ w2,
                          const float* __restrict__ b2, float* __restrict__ gate) {
    int b = blockIdx.x;
    int h = threadIdx.x >> 5;
    int lane = threadIdx.x & 31;
    const float* rr = r + (size_t)b * H4;
    const float* ww = w2 + (size_t)h * H4;
    float s = 0.f;
    for (int j = lane; j < H4; j += 32) s = fmaf(rr[j], ww[j], s);
    for (int off = 16; off > 0; off >>= 1) s += __shfl_down(s, off, 32);
    if (lane == 0) gate[b * HH + h] = s + b2[h];
}

// ---------------- top-k routing + BCE/LB/entropy/budget ----------------------
__global__ void k_routing_aux(const float* __restrict__ gate, const int* __restrict__ kmaxp,
                              float* __restrict__ act_out, float* __restrict__ scal) {
    __shared__ float af[64][8];
    __shared__ float bces[64], ents[64];
    int b = threadIdx.x;   // 64 threads
    float g[8];
#pragma unroll
    for (int h = 0; h < 8; ++h) g[h] = gate[b * 8 + h];
    int k = kmaxp[0]; k = k < 0 ? 0 : (k > 8 ? 8 : k);
    bool act[8] = {false, false, false, false, false, false, false, false};
    for (int s = 0; s < k; ++s) {
        int best = -1; float bv = -1e30f;
#pragma unroll
        for (int h = 0; h < 8; ++h)
            if (!act[h] && g[h] > bv) { bv = g[h]; best = h; }
        act[best] = true;
    }
    float m = -1e30f;
#pragma unroll
    for (int h = 0; h < 8; ++h) m = fmaxf(m, g[h]);
    float se = 0.f, ex[8];
#pragma unroll
    for (int h = 0; h < 8; ++h) { ex[h] = expf(g[h] - m); se += ex[h]; }
    float bce = 0.f, ent = 0.f;
#pragma unroll
    for (int h = 0; h < 8; ++h) {
        float t = act[h] ? 1.f : 0.f;
        bce += fmaxf(g[h], 0.f) - g[h] * t + log1pf(expf(-fabsf(g[h])));
        float p = ex[h] / se;
        ent -= p * logf(p + 1e-9f);
        af[b][h] = t;
        act_out[b * 8 + h] = t;
    }
    bces[b] = bce; ents[b] = ent;
    __syncthreads();
    if (b == 0) {
        float bsum = 0.f, esum = 0.f, asum = 0.f, lb = 0.f;
        for (int i = 0; i < 64; ++i) { bsum += bces[i]; esum += ents[i]; }
        for (int h = 0; h < 8; ++h) {
            float f = 0.f;
            for (int i = 0; i < 64; ++i) f += af[i][h];
            asum += f;
            float fr = f / 64.f - 0.125f;
            lb += fr * fr;
        }
        scal[0] = bsum / 512.f;   // bce mean
        scal[1] = lb;             // load balance
        scal[2] = esum / 64.f;    // entropy mean
        scal[3] = asum / 512.f;   // budget
    }
}

// ---------------- big GEMM via MFMA f16: logits[b][h][v] ---------------------
// Block: M=64 (4 waves x 16 rows), N=64, K chunked by 64, double-buffered LDS.
// W-tile staged TRANSPOSED in LDS as [v][k] (f16, k-stride 72 to dodge bank
// conflicts). Both A and B fragments use the same k-ordering k = g*8+j
// (g = lane>>4), so the MFMA contraction is layout-correct by construction.
#define KS 72                  // k-stride in f16 elems (64 + 8 pad)

__global__ __launch_bounds__(256, 4) void k_heads_gemm(
    const float* __restrict__ W, const _Float16* __restrict__ hA,
    float* __restrict__ out) {
    __shared__ __align__(16) _Float16 ldsB[2][64 * KS];
    const int h  = blockIdx.y;
    const int v0 = blockIdx.x * 64;
    const int tid = threadIdx.x;
    const int lane = tid & 63, wv = tid >> 6;
    const int lg = lane >> 4, lr = lane & 15;

    // staging map: thread -> (v column, 16 k's)
    const int v_s = tid & 63;
    const int ks0 = (tid >> 6) * 16;
    const float* wcol = W + (size_t)h * DD * VV + v0 + v_s;

    float rbuf[16];
    f32x4 acc[4];
#pragma unroll
    for (int nt = 0; nt < 4; ++nt) acc[nt] = (f32x4){0.f, 0.f, 0.f, 0.f};

#define LOAD_CHUNK(kc)                                                      \
    {                                                                       \
        const float* p_ = wcol + (size_t)((kc) * 64 + ks0) * VV;            \
        _Pragma("unroll")                                                   \
        for (int kk_ = 0; kk_ < 16; ++kk_) rbuf[kk_] = p_[(size_t)kk_ * VV]; \
    }

#define STORE_CHUNK(b_)                                                     \
    {                                                                       \
        f16x8 lo_, hi_;                                                     \
        _Pragma("unroll")                                                   \
        for (int kk_ = 0; kk_ < 8; ++kk_) {                                 \
            lo_[kk_] = (_Float16)rbuf[kk_];                                 \
            hi_[kk_] = (_Float16)rbuf[kk_ + 8];                             \
        }                                                                   \
        *(f16x8*)&ldsB[b_][v_s * KS + ks0]     = lo_;                       \
        *(f16x8*)&ldsB[b_][v_s * KS + ks0 + 8] = hi_;                       \
    }

    LOAD_CHUNK(0);
    STORE_CHUNK(0);
    __syncthreads();

    const _Float16* pa0 = hA + (size_t)(wv * 16 + lr) * DD + lg * 8;

    for (int kc = 0; kc < 16; ++kc) {
        if (kc < 15) LOAD_CHUNK(kc + 1);

        const _Float16* pa = pa0 + kc * 64;
        const _Float16* lb = &ldsB[kc & 1][lr * KS + lg * 8];
#pragma unroll
        for (int ks = 0; ks < 2; ++ks) {
            f16x8 fa = *(const f16x8*)(pa + ks * 32);
#pragma unroll
            for (int nt = 0; nt < 4; ++nt) {
                f16x8 fb = *(const f16x8*)(lb + nt * 16 * KS + ks * 32);
                acc[nt] = __builtin_amdgcn_mfma_f32_16x16x32_f16(fa, fb, acc[nt], 0, 0, 0);
            }
        }

        if (kc < 15) {
            STORE_CHUNK((kc + 1) & 1);
            __syncthreads();
        }
    }

    // epilogue: C/D layout col = lane&15 (n), row = (lane>>4)*4 + reg (m)
#pragma unroll
    for (int nt = 0; nt < 4; ++nt) {
#pragma unroll
        for (int q = 0; q < 4; ++q) {
            int m = wv * 16 + lg * 4 + q;
            int n = v0 + nt * 16 + lr;
            out[((size_t)m * HH + h) * VV + n] = acc[nt][q];
        }
    }
#undef LOAD_CHUNK
#undef STORE_CHUNK
}

// ---------------- masked CE per (b,h): two-pass log-softmax ------------------
__global__ __launch_bounds__(256) void k_ce(
    const float* __restrict__ logits, const float* __restrict__ act,
    const int* __restrict__ labels, float* __restrict__ nllv, float* __restrict__ cnt) {
    int p = blockIdx.x;   // b*8 + h
    const float* lp = logits + (size_t)p * VV;
    __shared__ float red[256];
    float m = -1e30f;
    for (int i = threadIdx.x; i < VV; i += 256) m = fmaxf(m, lp[i]);
    red[threadIdx.x] = m; __syncthreads();
    for (int s = 128; s > 0; s >>= 1) {
        if (threadIdx.x < s) red[threadIdx.x] = fmaxf(red[threadIdx.x], red[threadIdx.x + s]);
        __syncthreads();
    }
    m = red[0]; __syncthreads();
    float se = 0.f;
    for (int i = threadIdx.x; i < VV; i += 256) se += expf(lp[i] - m);
    red[threadIdx.x] = se; __syncthreads();
    for (int s = 128; s > 0; s >>= 1) {
        if (threadIdx.x < s) red[threadIdx.x] += red[threadIdx.x + s];
        __syncthreads();
    }
    if (threadIdx.x == 0) {
        int lab = labels[p];
        float nll = -(lp[lab] - m - logf(red[0]));
        bool valid = (act[p] > 0.5f) && (lab != 0);
        nllv[p] = valid ? nll : 0.f;
        cnt[p]  = valid ? 1.f : 0.f;
    }
}

// ---------------- final scalar loss ------------------------------------------
__global__ void k_final_loss(const float* __restrict__ nllv, const float* __restrict__ cnt,
                             const float* __restrict__ scal, float* __restrict__ lossp) {
    __shared__ float r1[256], r2[256];
    float a = nllv[threadIdx.x] + nllv[threadIdx.x + 256];
    float c = cnt[threadIdx.x]  + cnt[threadIdx.x + 256];
    r1[threadIdx.x] = a; r2[threadIdx.x] = c; __syncthreads();
    for (int s = 128; s > 0; s >>= 1) {
        if (threadIdx.x < s) { r1[threadIdx.x] += r1[threadIdx.x + s]; r2[threadIdx.x] += r2[threadIdx.x + s]; }
        __syncthreads();
    }
    if (threadIdx.x == 0) {
        float nv = r2[0] < 1.f ? 1.f : r2[0];
        float ce = r1[0] / nv;
        lossp[0] = ce + 1.0f * scal[0] + 0.2f * scal[1] + 0.01f * scal[2] + 0.05f * scal[3];
    }
}

extern "C" void kernel_launch(void* const* d_in, const int* in_sizes, int n_in,
                              void* d_out, int out_size, void* d_ws, size_t ws_size,
                              hipStream_t stream) {
    const float* hidden = (const float*)d_in[0];
    const float* w1     = (const float*)d_in[1];
    const float* b1     = (const float*)d_in[2];
    const float* w2     = (const float*)d_in[3];
    const float* b2     = (const float*)d_in[4];
    const float* W      = (const float*)d_in[5];
    const int*   labels = (const int*)d_in[6];
    const int*   kmaxp  = (const int*)d_in[7];

    float* ws  = (float*)d_ws;
    float* out = (float*)d_out;

    float* hT    = ws + OFF_HT;
    float* w1T   = ws + OFF_W1T;
    float* rpart = ws + OFF_RPART;
    float* r     = ws + OFF_R;
    float* nllv  = ws + OFF_NLL;
    float* cntv  = ws + OFF_CNT;
    float* scal  = ws + OFF_SCAL;
    _Float16* hA = (_Float16*)(ws + OFF_RPART);   // reused after k_router1_reduce

    float* logits = out + OFF_LOGITS;
    float* gate   = out + OFF_GATE;
    float* activ  = out + OFF_ACT;
    float* lossp  = out + OFF_LOSS;

    // 1. hidden [64][1024] -> hT [1024][64]
    k_transpose<<<dim3(32, 2), 256, 0, stream>>>(hidden, hT, BB, DD);
    // 2. w1 [4096][1024] -> w1T [1024][4096]
    k_transpose<<<dim3(32, 128), 256, 0, stream>>>(w1, w1T, H4, DD);
    // 3. router layer 1 partial GEMM
    k_router1_partial<<<dim3(16, DSPLIT), 256, 0, stream>>>(hT, w1T, rpart);
    // 4. reduce + bias + GELU
    k_router1_reduce<<<dim3(1024), 256, 0, stream>>>(rpart, b1, r);
    // 4b. hidden -> f16 (overwrites rpart space, which is now dead)
    k_h2f16<<<dim3(256), 256, 0, stream>>>(hidden, hA);
    // 5. router layer 2
    k_router2<<<dim3(64), 256, 0, stream>>>(r, w2, b2, gate);
    // 6. routing / aux losses
    k_routing_aux<<<dim3(1), 64, 0, stream>>>(gate, kmaxp, activ, scal);
    // 7. big GEMM (MFMA f16)
    k_heads_gemm<<<dim3(500, 8), 256, 0, stream>>>(W, hA, logits);
    // 8. masked CE
    k_ce<<<dim3(512), 256, 0, stream>>>(logits, activ, labels, nllv, cntv);
    // 9. final loss
    k_final_loss<<<dim3(1), 256, 0, stream>>>(nllv, cntv, scal, lossp);
}